// Round 7
// baseline (166.535 us; speedup 1.0000x reference)
//
#include <hip/hip_runtime.h>
#include <math.h>

typedef unsigned int u32;
typedef unsigned long long u64;

constexpr int N_IMG = 16;
constexpr int C_CLS = 80;
constexpr int H_DIM = 160;
constexpr int W_DIM = 160;
constexpr int L_LOC = H_DIM * W_DIM;   // 25600
constexpr int LC    = L_LOC * C_CLS;   // 2048000
constexpr int K_TOP = 1000;
constexpr int NB    = 1024;            // histogram buckets: (bits-KEY_BASE)>>16
constexpr int CAP   = 4096;            // sorted-candidate cap per image (32KB LDS)
constexpr int CAP_SPEC = 32768;        // speculative list cap per image
constexpr int GBUF  = 512;             // passA per-block LDS buffer (u32 refidx)
constexpr int GROUPS_PER_BLK = 1280;   // 5 iters x 256 threads; 5 blocks/plane
constexpr float THRESH = 0.05f;
constexpr u32 KEY_BASE = 119u << 23;   // 0x3B800000
constexpr float T0     = 0.7f;
constexpr float DELTA  = 0.05f;        // conservative slack in logit space
// buckets >= B_SAFE have lower bound > 0.7f, where spec is provably a superset
constexpr int B_SAFE  = ((0x3F340000u - KEY_BASE) >> 16);  // 948

// ---- workspace layout (bytes) ----
constexpr size_t WS_SCNT  = 0;                                       // N*4
constexpr size_t WS_OFLOW = 64;                                      // N*4
constexpr size_t WS_META  = 128;                                     // N*16 (.,.,done,.)
constexpr size_t WS_CTRL_WORDS = 128;                                // 512 B zeroed
constexpr size_t WS_SPEC  = 512;                                     // u32: 16*32768*4 = 2 MB
constexpr size_t WS_K2    = WS_SPEC + (size_t)N_IMG * CAP_SPEC * 4;  // u64: 16*32768*8 = 4 MB
constexpr size_t WS_SCTR  = WS_K2 + (size_t)N_IMG * CAP_SPEC * 8;    // N*L*4
constexpr size_t WS_XMIN  = WS_SCTR + (size_t)N_IMG * L_LOC * 4;     // N*L*4

__device__ inline float sigmoidf_acc(float x) { return 1.0f / (1.0f + expf(-x)); }

__device__ inline u32 score_bucket(u32 bits) {
    u32 b = (bits >= KEY_BASE) ? ((bits - KEY_BASE) >> 16) : 0u;
    return b > (u32)(NB - 1) ? (u32)(NB - 1) : b;
}

// ---- shared device helpers ----

// bitonic sort of sk[0..n2) descending (pads with 0 above M); barriers inside
__device__ inline void bitonic_desc(u64* sk, u32 M, int tid, int nthr) {
    u32 n2 = 1024; while (n2 < M) n2 <<= 1;
    for (u32 i = tid; i < n2; i += nthr) if (i >= M) sk[i] = 0ull;
    __syncthreads();
    for (u32 k = 2; k <= n2; k <<= 1) {
        for (u32 j = k >> 1; j > 0; j >>= 1) {
            for (u32 i = tid; i < n2; i += nthr) {
                u32 ixj = i ^ j;
                if (ixj > i) {
                    u64 a = sk[i], b = sk[ixj];
                    bool front = ((i & k) == 0);
                    if (front ? (a < b) : (a > b)) { sk[i] = b; sk[ixj] = a; }
                }
            }
            __syncthreads();
        }
    }
}

// decode + write the K output rows for image n
__device__ inline void emit_rows(int n, const u64* sk, u32 cand_slots, const u32* fill,
                                 const float* locations, const float* breg,
                                 const int* isz, float* out, int tid, int nthr) {
    float* ob = out;                                  // boxes  [N,K,4]
    float* os = out + (size_t)N_IMG * K_TOP * 4;      // scores [N,K]
    float* ol = os + (size_t)N_IMG * K_TOP;           // labels [N,K]
    float* ov = ol + (size_t)N_IMG * K_TOP;           // valid  [N,K]
    const float wimg = (float)isz[n * 2 + 1];
    const float himg = (float)isz[n * 2 + 0];
    const float* rn = breg + (size_t)n * 4 * L_LOC;
    for (int k = tid; k < K_TOP; k += nthr) {
        size_t slot = (size_t)n * K_TOP + k;
        if ((u32)k < cand_slots) {
            u64 kk = sk[k];
            u32 vb = (u32)(kk >> 32);
            u32 idx = ~(u32)(kk & 0xFFFFFFFFull);
            float val = __uint_as_float(vb);
            int loc = (int)(idx / (u32)C_CLS);
            int c = (int)(idx - (u32)loc * (u32)C_CLS);
            float lx = locations[loc * 2 + 0], ly = locations[loc * 2 + 1];
            float r0 = rn[0 * L_LOC + loc], r1 = rn[1 * L_LOC + loc];
            float r2 = rn[2 * L_LOC + loc], r3 = rn[3 * L_LOC + loc];
            float x1 = lx - r0, y1 = ly - r1, x2 = lx + r2, y2 = ly + r3;
            x1 = fminf(fmaxf(x1, 0.0f), wimg - 1.0f);
            y1 = fminf(fmaxf(y1, 0.0f), himg - 1.0f);
            x2 = fminf(fmaxf(x2, 0.0f), wimg - 1.0f);
            y2 = fminf(fmaxf(y2, 0.0f), himg - 1.0f);
            float wsz = x2 - x1 + 1.0f, hsz = y2 - y1 + 1.0f;
            bool v = (val > 0.0f) && (wsz >= 0.0f) && (hsz >= 0.0f);  // MIN_SIZE = 0
            float vf = v ? 1.0f : 0.0f;
            ob[slot * 4 + 0] = x1 * vf;
            ob[slot * 4 + 1] = y1 * vf;
            ob[slot * 4 + 2] = x2 * vf;
            ob[slot * 4 + 3] = y2 * vf;
            os[slot] = v ? sqrtf(fmaxf(val, 0.0f)) : 0.0f;
            ol[slot] = (float)(c + 1);
            ov[slot] = vf;
        } else {
            u32 fi = fill ? fill[k - (int)cand_slots] : 0u;
            ob[slot * 4 + 0] = 0.0f; ob[slot * 4 + 1] = 0.0f;
            ob[slot * 4 + 2] = 0.0f; ob[slot * 4 + 3] = 0.0f;
            os[slot] = 0.0f;
            ol[slot] = (float)((int)(fi % (u32)C_CLS) + 1);
            ov[slot] = 0.0f;
        }
    }
}

// --- kernel 1: zero control block; sigmoid(centerness); per-location logit threshold ---
__global__ void prep_kernel(const float* __restrict__ ctr, float* __restrict__ sctr,
                            float* __restrict__ xmin, u32* __restrict__ ws32) {
    int i = blockIdx.x * blockDim.x + threadIdx.x;
    if (i < (int)WS_CTRL_WORDS) ws32[i] = 0u;
    if (i >= N_IMG * L_LOC) return;
    float s = sigmoidf_acc(ctr[i]);
    sctr[i] = s;
    float t = T0 / s;                       // need sigmoid(x) >= t for score >= T0
    float xm;
    if (t >= 1.0f) xm = 3.0e38f;            // impossible at this location
    else xm = logf(t / (1.0f - t)) - DELTA; // logit(t) with conservative slack
    xmin[i] = xm;
}

// --- kernel 2 (hot pass): linear-indexed batched compare; append refidx of survivors ---
// grid (5, C_CLS, N_IMG), block 256. Each block: 1280 contiguous float4-groups of one
// class plane. No div/mod in the loop; 10 loads batched up front.
__global__ __launch_bounds__(256) void passA_kernel(
        const float* __restrict__ cls, const float* __restrict__ xmin,
        u32* __restrict__ spec, u32* __restrict__ scnt, u32* __restrict__ oflow) {
    __shared__ u32 sbuf[GBUF];
    __shared__ u32 lcnt, gbase, lof;
    const int tid = threadIdx.x;
    const u32 n = blockIdx.z, cc = blockIdx.y;
    if (tid == 0) { lcnt = 0; lof = 0; }
    __syncthreads();
    const u32 g0 = blockIdx.x * (u32)GROUPS_PER_BLK;            // group offset in plane
    const float4* cp = reinterpret_cast<const float4*>(
        cls + (size_t)n * LC + (size_t)cc * L_LOC) + g0;
    const float4* xp = reinterpret_cast<const float4*>(
        xmin + (size_t)n * L_LOC) + g0;
    // batched loads: 10 independent 16B loads in flight
    float4 cv0 = cp[tid],        cv1 = cp[256 + tid],  cv2 = cp[512 + tid];
    float4 cv3 = cp[768 + tid],  cv4 = cp[1024 + tid];
    float4 xv0 = xp[tid],        xv1 = xp[256 + tid],  xv2 = xp[512 + tid];
    float4 xv3 = xp[768 + tid],  xv4 = xp[1024 + tid];
    u32 mk = 0u;
    mk |= (cv0.x >= xv0.x) ? 0x00001u : 0u; mk |= (cv0.y >= xv0.y) ? 0x00002u : 0u;
    mk |= (cv0.z >= xv0.z) ? 0x00004u : 0u; mk |= (cv0.w >= xv0.w) ? 0x00008u : 0u;
    mk |= (cv1.x >= xv1.x) ? 0x00010u : 0u; mk |= (cv1.y >= xv1.y) ? 0x00020u : 0u;
    mk |= (cv1.z >= xv1.z) ? 0x00040u : 0u; mk |= (cv1.w >= xv1.w) ? 0x00080u : 0u;
    mk |= (cv2.x >= xv2.x) ? 0x00100u : 0u; mk |= (cv2.y >= xv2.y) ? 0x00200u : 0u;
    mk |= (cv2.z >= xv2.z) ? 0x00400u : 0u; mk |= (cv2.w >= xv2.w) ? 0x00800u : 0u;
    mk |= (cv3.x >= xv3.x) ? 0x01000u : 0u; mk |= (cv3.y >= xv3.y) ? 0x02000u : 0u;
    mk |= (cv3.z >= xv3.z) ? 0x04000u : 0u; mk |= (cv3.w >= xv3.w) ? 0x08000u : 0u;
    mk |= (cv4.x >= xv4.x) ? 0x10000u : 0u; mk |= (cv4.y >= xv4.y) ? 0x20000u : 0u;
    mk |= (cv4.z >= xv4.z) ? 0x40000u : 0u; mk |= (cv4.w >= xv4.w) ? 0x80000u : 0u;
    // survivors: ~10 per wave total; iterate set bits (index-only append, no expf)
    const u32 loc_base = g0 * 4u;
    while (__ballot(mk != 0u)) {
        if (mk) {
            int b = __ffs(mk) - 1; mk &= mk - 1;
            u32 loc = loc_base + (u32)(((b >> 2) * 256 + tid) * 4 + (b & 3));
            u32 p = atomicAdd(&lcnt, 1u);
            if (p < (u32)GBUF) sbuf[p] = loc * (u32)C_CLS + cc;
            else lof = 1u;
        }
    }
    __syncthreads();
    u32 m_ = lcnt > (u32)GBUF ? (u32)GBUF : lcnt;
    if (tid == 0) {
        gbase = m_ ? atomicAdd(&scnt[n], m_) : 0u;
        if (lof || lcnt > (u32)GBUF) atomicOr(&oflow[n], 1u);
        if (m_ && gbase + m_ > (u32)CAP_SPEC) atomicOr(&oflow[n], 1u);
    }
    __syncthreads();
    u32* sp = spec + (size_t)n * CAP_SPEC;
    for (u32 i = tid; i < m_; i += 256) {
        u32 pos = gbase + i;
        if (pos < (u32)CAP_SPEC) sp[pos] = sbuf[i];
    }
}

// --- kernel 3 (FAST): score the spec list; hist; cutoff; filter; sort; emit ---
__global__ __launch_bounds__(1024) void fastB_kernel(
        const float* __restrict__ cls, const float* __restrict__ sctr,
        const u32* __restrict__ spec, const u32* __restrict__ scnt,
        const u32* __restrict__ oflow, u64* __restrict__ k2g,
        u32* __restrict__ meta, const float* __restrict__ locations,
        const float* __restrict__ breg, const int* __restrict__ isz,
        float* __restrict__ out) {
    __shared__ u32 lh[NB];
    __shared__ u64 sk[CAP];
    __shared__ u32 s_b, s_cnt, s_lcnt;
    const int n = blockIdx.x;
    const int tid = threadIdx.x;
    if (oflow[n]) return;                    // slow path handles
    lh[tid] = 0u;
    if (tid == 0) { s_b = 0xFFFFFFFFu; s_lcnt = 0; s_cnt = 0; }
    __syncthreads();
    u32 M = scnt[n]; if (M > (u32)CAP_SPEC) M = (u32)CAP_SPEC;
    const float* cls_n = cls + (size_t)n * LC;
    const float* sc_n = sctr + (size_t)n * L_LOC;
    const u32* sp = spec + (size_t)n * CAP_SPEC;
    u64* k2 = k2g + (size_t)n * CAP_SPEC;
    // pass 1: exact scores (reference formula) + histogram
    for (u32 i = tid; i < M; i += 1024) {
        u32 r = sp[i];
        u32 loc = r / (u32)C_CLS;
        u32 c = r - loc * (u32)C_CLS;
        float x = cls_n[(size_t)c * L_LOC + loc];
        float s = sigmoidf_acc(x);
        float scr = s * sc_n[loc];
        u32 bits = __float_as_uint(scr);
        k2[i] = ((u64)bits << 32) | (u32)(~r);   // value desc, idx asc
        atomicAdd(&lh[score_bucket(bits)], 1u);
    }
    __syncthreads();
    // suffix sums: lh[b] = count with bucket >= b
    for (u32 off = 1; off < (u32)NB; off <<= 1) {
        u32 add = (tid + off < (u32)NB) ? lh[tid + off] : 0u;
        __syncthreads();
        lh[tid] += add;
        __syncthreads();
    }
    if (lh[tid] >= (u32)K_TOP && (tid == NB - 1 || lh[tid + 1] < (u32)K_TOP)) {
        s_b = (u32)tid; s_cnt = lh[tid];
    }
    __syncthreads();
    u32 bstar = s_b;
    bool valid = (bstar != 0xFFFFFFFFu) && (bstar >= (u32)B_SAFE) &&
                 (s_cnt <= (u32)CAP);
    if (!valid) return;                      // meta.done stays 0 -> slowC handles
    if (tid == 0) meta[n * 4 + 2] = 1u;
    const u32 keymin = KEY_BASE + (bstar << 16);
    for (u32 i = tid; i < M; i += 1024) {
        u64 e = k2[i];
        if ((u32)(e >> 32) >= keymin) {
            u32 p = atomicAdd(&s_lcnt, 1u);
            if (p < (u32)CAP) sk[p] = e;
        }
    }
    __syncthreads();
    u32 Mk = s_lcnt;                         // == s_cnt <= CAP, >= K
    bitonic_desc(sk, Mk, tid, 1024);
    emit_rows(n, sk, (u32)K_TOP, nullptr, locations, breg, isz, out, tid, 1024);
}

// --- kernel 4 (SLOW, gated; never taken in practice): full per-image pipeline ---
__global__ __launch_bounds__(1024) void slowC_kernel(
        const float* __restrict__ cls, const float* __restrict__ sctr,
        const u32* __restrict__ meta, const float* __restrict__ locations,
        const float* __restrict__ breg, const int* __restrict__ isz,
        float* __restrict__ out) {
    const int n = blockIdx.x;
    if (meta[n * 4 + 2] != 0u) return;
    __shared__ u32 lh[NB];                   // hist -> suffix -> scan scratch
    __shared__ u64 sk[CAP];
    __shared__ u32 fill[K_TOP];
    __shared__ u32 s_b, s_lcnt, s_filled;
    const int tid = threadIdx.x;
    lh[tid] = 0u;
    if (tid == 0) { s_b = 0xFFFFFFFFu; s_lcnt = 0; s_filled = 0; }
    __syncthreads();
    const float* cls_n = cls + (size_t)n * LC;
    const float* sc_n = sctr + (size_t)n * L_LOC;
    // phase 1: full histogram (coalesced over [C][L] plane order)
    for (u32 f = tid; f < (u32)LC; f += 1024) {
        float s = sigmoidf_acc(cls_n[f]);
        if (s > THRESH) {
            float scr = s * sc_n[f % (u32)L_LOC];
            atomicAdd(&lh[score_bucket(__float_as_uint(scr))], 1u);
        }
    }
    __syncthreads();
    // phase 2: suffix sums + cutoff
    for (u32 off = 1; off < (u32)NB; off <<= 1) {
        u32 add = (tid + off < (u32)NB) ? lh[tid + off] : 0u;
        __syncthreads();
        lh[tid] += add;
        __syncthreads();
    }
    if (lh[tid] >= (u32)K_TOP && (tid == NB - 1 || lh[tid + 1] < (u32)K_TOP))
        s_b = (u32)tid;
    __syncthreads();
    const u32 total = lh[0];
    const u32 keymin = (s_b != 0xFFFFFFFFu) ? (KEY_BASE + (s_b << 16)) : 0u;
    __syncthreads();
    // phase 3: gather candidates >= keymin
    for (u32 f = tid; f < (u32)LC; f += 1024) {
        float s = sigmoidf_acc(cls_n[f]);
        if (s > THRESH) {
            u32 loc = f % (u32)L_LOC;
            u32 c = f / (u32)L_LOC;
            float scr = s * sc_n[loc];
            u32 bits = __float_as_uint(scr);
            if (bits >= keymin) {
                u32 p = atomicAdd(&s_lcnt, 1u);
                if (p < (u32)CAP)
                    sk[p] = ((u64)bits << 32) | (u32)(~(loc * (u32)C_CLS + c));
            }
        }
    }
    __syncthreads();
    u32 M = s_lcnt > (u32)CAP ? (u32)CAP : s_lcnt;
    u32 cand_slots = total < (u32)K_TOP ? total : (u32)K_TOP;
    // phase 4: fallback fill list (smallest non-candidate flat (L,C) indices)
    if (total < (u32)K_TOP) {
        const u32 need = (u32)K_TOP - total;
        for (u32 basei = 0; basei < (u32)LC; basei += 1024) {
            u32 idx = basei + tid;
            u32 flag = 0;
            if (idx < (u32)LC) {
                u32 loc = idx / (u32)C_CLS;
                u32 c = idx - loc * (u32)C_CLS;
                float x = cls_n[(size_t)c * L_LOC + loc];
                flag = (sigmoidf_acc(x) > THRESH) ? 0u : 1u;
            }
            lh[tid] = flag;
            __syncthreads();
            for (u32 off = 1; off < 1024; off <<= 1) {
                u32 v = (tid >= (int)off) ? lh[tid - off] : 0u;
                __syncthreads();
                lh[tid] += v;
                __syncthreads();
            }
            u32 excl = lh[tid] - flag;
            u32 pos = s_filled + excl;
            if (flag && pos < need) fill[pos] = idx;
            __syncthreads();
            if (tid == 0) s_filled += lh[1023];
            __syncthreads();
            if (s_filled >= need) break;
        }
    }
    // phase 5+6: sort + emit
    bitonic_desc(sk, M, tid, 1024);
    emit_rows(n, sk, cand_slots, fill, locations, breg, isz, out, tid, 1024);
}

extern "C" void kernel_launch(void* const* d_in, const int* in_sizes, int n_in,
                              void* d_out, int out_size, void* d_ws, size_t ws_size,
                              hipStream_t stream) {
    const float* locations = (const float*)d_in[0];
    const float* cls       = (const float*)d_in[1];
    const float* breg      = (const float*)d_in[2];
    const float* ctr       = (const float*)d_in[3];
    const int*   isz       = (const int*)d_in[4];
    float* out = (float*)d_out;

    char* ws = (char*)d_ws;
    u32* ws32  = (u32*)ws;
    u32* scnt  = (u32*)(ws + WS_SCNT);
    u32* oflow = (u32*)(ws + WS_OFLOW);
    u32* meta  = (u32*)(ws + WS_META);
    u32* spec  = (u32*)(ws + WS_SPEC);
    u64* k2g   = (u64*)(ws + WS_K2);
    float* sctr = (float*)(ws + WS_SCTR);
    float* xmin = (float*)(ws + WS_XMIN);

    prep_kernel<<<(N_IMG * L_LOC + 255) / 256, 256, 0, stream>>>(ctr, sctr, xmin, ws32);
    passA_kernel<<<dim3(L_LOC / 4 / GROUPS_PER_BLK, C_CLS, N_IMG), 256, 0, stream>>>(
        cls, xmin, spec, scnt, oflow);
    fastB_kernel<<<N_IMG, 1024, 0, stream>>>(cls, sctr, spec, scnt, oflow, k2g, meta,
                                             locations, breg, isz, out);
    slowC_kernel<<<N_IMG, 1024, 0, stream>>>(cls, sctr, meta, locations, breg, isz, out);
}

// Round 8
// 140.871 us; speedup vs baseline: 1.1822x; 1.1822x over previous
//
#include <hip/hip_runtime.h>
#include <math.h>

typedef unsigned int u32;
typedef unsigned long long u64;

constexpr int N_IMG = 16;
constexpr int C_CLS = 80;
constexpr int H_DIM = 160;
constexpr int W_DIM = 160;
constexpr int L_LOC = H_DIM * W_DIM;   // 25600
constexpr int LC    = L_LOC * C_CLS;   // 2048000
constexpr int K_TOP = 1000;
constexpr int NB    = 1024;            // histogram buckets: (bits-KEY_BASE)>>16
constexpr int CAP   = 4096;            // sorted-candidate cap per image (32KB LDS)
constexpr int CAP_SPEC = 32768;        // speculative list cap per image
constexpr int GBUF  = 512;             // passA per-block LDS buffer (u64)
constexpr int GROUPS_PER_BLK = 1280;   // 5 iters x 256 threads; 5 blocks/plane
constexpr float THRESH = 0.05f;
constexpr u32 KEY_BASE = 119u << 23;   // 0x3B800000
constexpr float T0     = 0.7f;
constexpr float DELTA  = 0.05f;        // conservative slack in logit space
// buckets >= B_SAFE have lower bound > 0.7f, where spec is provably a superset
constexpr int B_SAFE  = ((0x3F340000u - KEY_BASE) >> 16);  // 948

// ---- workspace layout (bytes) ----
constexpr size_t WS_SCNT  = 0;                                       // N*4
constexpr size_t WS_OFLOW = 64;                                      // N*4
constexpr size_t WS_META  = 128;                                     // N*16 (.,.,done,.)
constexpr size_t WS_CTRL_WORDS = 128;                                // 512 B zeroed
constexpr size_t WS_GHIST = 512;                                     // 16*1024*4 = 64 KB
constexpr size_t WS_SPEC  = WS_GHIST + (size_t)N_IMG * NB * 4;       // u64: 16*32768*8 = 4 MB
constexpr size_t WS_SCTR  = WS_SPEC + (size_t)N_IMG * CAP_SPEC * 8;  // N*L*4
constexpr size_t WS_XMIN  = WS_SCTR + (size_t)N_IMG * L_LOC * 4;     // N*L*4

__device__ inline float sigmoidf_acc(float x) { return 1.0f / (1.0f + expf(-x)); }

__device__ inline u32 score_bucket(u32 bits) {
    u32 b = (bits >= KEY_BASE) ? ((bits - KEY_BASE) >> 16) : 0u;
    return b > (u32)(NB - 1) ? (u32)(NB - 1) : b;
}

// ---- shared device helpers ----

// bitonic sort of sk[0..n2) descending (pads with 0 above M); barriers inside
__device__ inline void bitonic_desc(u64* sk, u32 M, int tid, int nthr) {
    u32 n2 = 1024; while (n2 < M) n2 <<= 1;
    for (u32 i = tid; i < n2; i += nthr) if (i >= M) sk[i] = 0ull;
    __syncthreads();
    for (u32 k = 2; k <= n2; k <<= 1) {
        for (u32 j = k >> 1; j > 0; j >>= 1) {
            for (u32 i = tid; i < n2; i += nthr) {
                u32 ixj = i ^ j;
                if (ixj > i) {
                    u64 a = sk[i], b = sk[ixj];
                    bool front = ((i & k) == 0);
                    if (front ? (a < b) : (a > b)) { sk[i] = b; sk[ixj] = a; }
                }
            }
            __syncthreads();
        }
    }
}

// decode + write the K output rows for image n
__device__ inline void emit_rows(int n, const u64* sk, u32 cand_slots, const u32* fill,
                                 const float* locations, const float* breg,
                                 const int* isz, float* out, int tid, int nthr) {
    float* ob = out;                                  // boxes  [N,K,4]
    float* os = out + (size_t)N_IMG * K_TOP * 4;      // scores [N,K]
    float* ol = os + (size_t)N_IMG * K_TOP;           // labels [N,K]
    float* ov = ol + (size_t)N_IMG * K_TOP;           // valid  [N,K]
    const float wimg = (float)isz[n * 2 + 1];
    const float himg = (float)isz[n * 2 + 0];
    const float* rn = breg + (size_t)n * 4 * L_LOC;
    for (int k = tid; k < K_TOP; k += nthr) {
        size_t slot = (size_t)n * K_TOP + k;
        if ((u32)k < cand_slots) {
            u64 kk = sk[k];
            u32 vb = (u32)(kk >> 32);
            u32 idx = ~(u32)(kk & 0xFFFFFFFFull);
            float val = __uint_as_float(vb);
            int loc = (int)(idx / (u32)C_CLS);
            int c = (int)(idx - (u32)loc * (u32)C_CLS);
            float lx = locations[loc * 2 + 0], ly = locations[loc * 2 + 1];
            float r0 = rn[0 * L_LOC + loc], r1 = rn[1 * L_LOC + loc];
            float r2 = rn[2 * L_LOC + loc], r3 = rn[3 * L_LOC + loc];
            float x1 = lx - r0, y1 = ly - r1, x2 = lx + r2, y2 = ly + r3;
            x1 = fminf(fmaxf(x1, 0.0f), wimg - 1.0f);
            y1 = fminf(fmaxf(y1, 0.0f), himg - 1.0f);
            x2 = fminf(fmaxf(x2, 0.0f), wimg - 1.0f);
            y2 = fminf(fmaxf(y2, 0.0f), himg - 1.0f);
            float wsz = x2 - x1 + 1.0f, hsz = y2 - y1 + 1.0f;
            bool v = (val > 0.0f) && (wsz >= 0.0f) && (hsz >= 0.0f);  // MIN_SIZE = 0
            float vf = v ? 1.0f : 0.0f;
            ob[slot * 4 + 0] = x1 * vf;
            ob[slot * 4 + 1] = y1 * vf;
            ob[slot * 4 + 2] = x2 * vf;
            ob[slot * 4 + 3] = y2 * vf;
            os[slot] = v ? sqrtf(fmaxf(val, 0.0f)) : 0.0f;
            ol[slot] = (float)(c + 1);
            ov[slot] = vf;
        } else {
            u32 fi = fill ? fill[k - (int)cand_slots] : 0u;
            ob[slot * 4 + 0] = 0.0f; ob[slot * 4 + 1] = 0.0f;
            ob[slot * 4 + 2] = 0.0f; ob[slot * 4 + 3] = 0.0f;
            os[slot] = 0.0f;
            ol[slot] = (float)((int)(fi % (u32)C_CLS) + 1);
            ov[slot] = 0.0f;
        }
    }
}

// --- kernel 1: zero control+ghist; sigmoid(centerness); per-location logit threshold ---
__global__ void prep_kernel(const float* __restrict__ ctr, float* __restrict__ sctr,
                            float* __restrict__ xmin, u32* __restrict__ ws32) {
    int i = blockIdx.x * blockDim.x + threadIdx.x;
    if (i < (int)WS_CTRL_WORDS) ws32[i] = 0u;
    if (i < N_IMG * NB) ws32[WS_GHIST / 4 + i] = 0u;
    if (i >= N_IMG * L_LOC) return;
    float s = sigmoidf_acc(ctr[i]);
    sctr[i] = s;
    float t = T0 / s;                       // need sigmoid(x) >= t for score >= T0
    float xm;
    if (t >= 1.0f) xm = 3.0e38f;            // impossible at this location
    else xm = logf(t / (1.0f - t)) - DELTA; // logit(t) with conservative slack
    xmin[i] = xm;
}

// --- kernel 2 (hot pass): batched compare; survivors scored in-register ---
// grid (5, C_CLS, N_IMG), block 256. Each block: 1280 contiguous float4-groups of one
// class plane. Survivor (~0.8%): exact score from the register value + L2-hit sctr,
// LDS hist + u64 append; sparse global hist merge; one global atomic per block.
__global__ __launch_bounds__(256) void passA_kernel(
        const float* __restrict__ cls, const float* __restrict__ xmin,
        const float* __restrict__ sctr, u64* __restrict__ spec,
        u32* __restrict__ scnt, u32* __restrict__ oflow, u32* __restrict__ ghist) {
    __shared__ u32 lh[NB];
    __shared__ u64 sbuf[GBUF];
    __shared__ u32 lcnt, gbase, lof;
    const int tid = threadIdx.x;
    const u32 n = blockIdx.z, cc = blockIdx.y;
    for (int b = tid; b < NB; b += 256) lh[b] = 0u;
    if (tid == 0) { lcnt = 0; lof = 0; }
    __syncthreads();
    const u32 g0 = blockIdx.x * (u32)GROUPS_PER_BLK;            // group offset in plane
    const float4* cp = reinterpret_cast<const float4*>(
        cls + (size_t)n * LC + (size_t)cc * L_LOC) + g0;
    const float4* xp = reinterpret_cast<const float4*>(
        xmin + (size_t)n * L_LOC) + g0;
    const float* sc_n = sctr + (size_t)n * L_LOC;
    // batched loads: 10 independent 16B loads in flight
    float4 cv[5], xv[5];
#pragma unroll
    for (int q = 0; q < 5; ++q) { cv[q] = cp[q * 256 + tid]; xv[q] = xp[q * 256 + tid]; }
    const u32 loc0 = g0 * 4u;
#pragma unroll
    for (int q = 0; q < 5; ++q) {
#pragma unroll
        for (int j = 0; j < 4; ++j) {
            float x = (j == 0) ? cv[q].x : (j == 1) ? cv[q].y : (j == 2) ? cv[q].z : cv[q].w;
            float m = (j == 0) ? xv[q].x : (j == 1) ? xv[q].y : (j == 2) ? xv[q].z : xv[q].w;
            if (x >= m) {
                u32 loc = loc0 + (u32)((q * 256 + tid) * 4 + j);
                float s = sigmoidf_acc(x);               // exact reference formula
                float scr = s * sc_n[loc];
                u32 bits = __float_as_uint(scr);
                atomicAdd(&lh[score_bucket(bits)], 1u);
                u32 p = atomicAdd(&lcnt, 1u);
                if (p < (u32)GBUF)
                    sbuf[p] = ((u64)bits << 32) | (u32)(~(loc * (u32)C_CLS + cc));
                else lof = 1u;
            }
        }
    }
    __syncthreads();
    // sparse merge of per-block hist (few non-zero buckets)
    u32* hn = ghist + (size_t)n * NB;
    for (int b = tid; b < NB; b += 256) {
        u32 v = lh[b];
        if (v) atomicAdd(&hn[b], v);
    }
    u32 m_ = lcnt > (u32)GBUF ? (u32)GBUF : lcnt;
    if (tid == 0) {
        gbase = m_ ? atomicAdd(&scnt[n], m_) : 0u;
        if (lof || lcnt > (u32)GBUF) atomicOr(&oflow[n], 1u);
        if (m_ && gbase + m_ > (u32)CAP_SPEC) atomicOr(&oflow[n], 1u);
    }
    __syncthreads();
    u64* sp = spec + (size_t)n * CAP_SPEC;
    for (u32 i = tid; i < m_; i += 256) {
        u32 pos = gbase + i;
        if (pos < (u32)CAP_SPEC) sp[pos] = sbuf[i];
    }
}

// --- kernel 3 (FAST finisher): suffix-scan ghist; filter spec (coalesced); sort; emit ---
__global__ __launch_bounds__(1024) void finishB_kernel(
        const u32* __restrict__ ghist, const u32* __restrict__ scnt,
        const u32* __restrict__ oflow, const u64* __restrict__ spec,
        u32* __restrict__ meta, const float* __restrict__ locations,
        const float* __restrict__ breg, const int* __restrict__ isz,
        float* __restrict__ out) {
    __shared__ u32 lh[NB];
    __shared__ u64 sk[CAP];
    __shared__ u32 s_b, s_cnt, s_lcnt;
    const int n = blockIdx.x;
    const int tid = threadIdx.x;
    if (oflow[n]) return;                    // slow path handles
    lh[tid] = ghist[(size_t)n * NB + tid];
    if (tid == 0) { s_b = 0xFFFFFFFFu; s_lcnt = 0; s_cnt = 0; }
    __syncthreads();
    // suffix sums: lh[b] = count with bucket >= b
    for (u32 off = 1; off < (u32)NB; off <<= 1) {
        u32 add = (tid + off < (u32)NB) ? lh[tid + off] : 0u;
        __syncthreads();
        lh[tid] += add;
        __syncthreads();
    }
    if (lh[tid] >= (u32)K_TOP && (tid == NB - 1 || lh[tid + 1] < (u32)K_TOP)) {
        s_b = (u32)tid; s_cnt = lh[tid];
    }
    __syncthreads();
    u32 bstar = s_b;
    bool valid = (bstar != 0xFFFFFFFFu) && (bstar >= (u32)B_SAFE) &&
                 (s_cnt <= (u32)CAP) && (scnt[n] <= (u32)CAP_SPEC);
    if (!valid) return;                      // meta.done stays 0 -> slowC handles
    if (tid == 0) meta[n * 4 + 2] = 1u;
    const u32 keymin = KEY_BASE + (bstar << 16);
    const u32 M = scnt[n];
    const u64* sp = spec + (size_t)n * CAP_SPEC;
    for (u32 i = tid; i < M; i += 1024) {    // coalesced u64 reads
        u64 e = sp[i];
        if ((u32)(e >> 32) >= keymin) {
            u32 p = atomicAdd(&s_lcnt, 1u);
            if (p < (u32)CAP) sk[p] = e;
        }
    }
    __syncthreads();
    u32 Mk = s_lcnt;                         // == s_cnt <= CAP, >= K
    bitonic_desc(sk, Mk, tid, 1024);
    emit_rows(n, sk, (u32)K_TOP, nullptr, locations, breg, isz, out, tid, 1024);
}

// --- kernel 4 (SLOW, gated; never taken in practice): full per-image pipeline ---
__global__ __launch_bounds__(1024) void slowC_kernel(
        const float* __restrict__ cls, const float* __restrict__ sctr,
        const u32* __restrict__ meta, const float* __restrict__ locations,
        const float* __restrict__ breg, const int* __restrict__ isz,
        float* __restrict__ out) {
    const int n = blockIdx.x;
    if (meta[n * 4 + 2] != 0u) return;
    __shared__ u32 lh[NB];                   // hist -> suffix -> scan scratch
    __shared__ u64 sk[CAP];
    __shared__ u32 fill[K_TOP];
    __shared__ u32 s_b, s_lcnt, s_filled;
    const int tid = threadIdx.x;
    lh[tid] = 0u;
    if (tid == 0) { s_b = 0xFFFFFFFFu; s_lcnt = 0; s_filled = 0; }
    __syncthreads();
    const float* cls_n = cls + (size_t)n * LC;
    const float* sc_n = sctr + (size_t)n * L_LOC;
    // phase 1: full histogram (coalesced over [C][L] plane order)
    for (u32 f = tid; f < (u32)LC; f += 1024) {
        float s = sigmoidf_acc(cls_n[f]);
        if (s > THRESH) {
            float scr = s * sc_n[f % (u32)L_LOC];
            atomicAdd(&lh[score_bucket(__float_as_uint(scr))], 1u);
        }
    }
    __syncthreads();
    // phase 2: suffix sums + cutoff
    for (u32 off = 1; off < (u32)NB; off <<= 1) {
        u32 add = (tid + off < (u32)NB) ? lh[tid + off] : 0u;
        __syncthreads();
        lh[tid] += add;
        __syncthreads();
    }
    if (lh[tid] >= (u32)K_TOP && (tid == NB - 1 || lh[tid + 1] < (u32)K_TOP))
        s_b = (u32)tid;
    __syncthreads();
    const u32 total = lh[0];
    const u32 keymin = (s_b != 0xFFFFFFFFu) ? (KEY_BASE + (s_b << 16)) : 0u;
    __syncthreads();
    // phase 3: gather candidates >= keymin
    for (u32 f = tid; f < (u32)LC; f += 1024) {
        float s = sigmoidf_acc(cls_n[f]);
        if (s > THRESH) {
            u32 loc = f % (u32)L_LOC;
            u32 c = f / (u32)L_LOC;
            float scr = s * sc_n[loc];
            u32 bits = __float_as_uint(scr);
            if (bits >= keymin) {
                u32 p = atomicAdd(&s_lcnt, 1u);
                if (p < (u32)CAP)
                    sk[p] = ((u64)bits << 32) | (u32)(~(loc * (u32)C_CLS + c));
            }
        }
    }
    __syncthreads();
    u32 M = s_lcnt > (u32)CAP ? (u32)CAP : s_lcnt;
    u32 cand_slots = total < (u32)K_TOP ? total : (u32)K_TOP;
    // phase 4: fallback fill list (smallest non-candidate flat (L,C) indices)
    if (total < (u32)K_TOP) {
        const u32 need = (u32)K_TOP - total;
        for (u32 basei = 0; basei < (u32)LC; basei += 1024) {
            u32 idx = basei + tid;
            u32 flag = 0;
            if (idx < (u32)LC) {
                u32 loc = idx / (u32)C_CLS;
                u32 c = idx - loc * (u32)C_CLS;
                float x = cls_n[(size_t)c * L_LOC + loc];
                flag = (sigmoidf_acc(x) > THRESH) ? 0u : 1u;
            }
            lh[tid] = flag;
            __syncthreads();
            for (u32 off = 1; off < 1024; off <<= 1) {
                u32 v = (tid >= (int)off) ? lh[tid - off] : 0u;
                __syncthreads();
                lh[tid] += v;
                __syncthreads();
            }
            u32 excl = lh[tid] - flag;
            u32 pos = s_filled + excl;
            if (flag && pos < need) fill[pos] = idx;
            __syncthreads();
            if (tid == 0) s_filled += lh[1023];
            __syncthreads();
            if (s_filled >= need) break;
        }
    }
    // phase 5+6: sort + emit
    bitonic_desc(sk, M, tid, 1024);
    emit_rows(n, sk, cand_slots, fill, locations, breg, isz, out, tid, 1024);
}

extern "C" void kernel_launch(void* const* d_in, const int* in_sizes, int n_in,
                              void* d_out, int out_size, void* d_ws, size_t ws_size,
                              hipStream_t stream) {
    const float* locations = (const float*)d_in[0];
    const float* cls       = (const float*)d_in[1];
    const float* breg      = (const float*)d_in[2];
    const float* ctr       = (const float*)d_in[3];
    const int*   isz       = (const int*)d_in[4];
    float* out = (float*)d_out;

    char* ws = (char*)d_ws;
    u32* ws32  = (u32*)ws;
    u32* scnt  = (u32*)(ws + WS_SCNT);
    u32* oflow = (u32*)(ws + WS_OFLOW);
    u32* meta  = (u32*)(ws + WS_META);
    u32* ghist = (u32*)(ws + WS_GHIST);
    u64* spec  = (u64*)(ws + WS_SPEC);
    float* sctr = (float*)(ws + WS_SCTR);
    float* xmin = (float*)(ws + WS_XMIN);

    prep_kernel<<<(N_IMG * L_LOC + 255) / 256, 256, 0, stream>>>(ctr, sctr, xmin, ws32);
    passA_kernel<<<dim3(L_LOC / 4 / GROUPS_PER_BLK, C_CLS, N_IMG), 256, 0, stream>>>(
        cls, xmin, sctr, spec, scnt, oflow, ghist);
    finishB_kernel<<<N_IMG, 1024, 0, stream>>>(ghist, scnt, oflow, spec, meta,
                                               locations, breg, isz, out);
    slowC_kernel<<<N_IMG, 1024, 0, stream>>>(cls, sctr, meta, locations, breg, isz, out);
}

// Round 9
// 101.684 us; speedup vs baseline: 1.6378x; 1.3854x over previous
//
#include <hip/hip_runtime.h>
#include <math.h>

typedef unsigned int u32;
typedef unsigned long long u64;

constexpr int N_IMG = 16;
constexpr int C_CLS = 80;
constexpr int H_DIM = 160;
constexpr int W_DIM = 160;
constexpr int L_LOC = H_DIM * W_DIM;   // 25600
constexpr int LC    = L_LOC * C_CLS;   // 2048000
constexpr int K_TOP = 1000;
constexpr int NB    = 1024;            // histogram buckets: (bits-KEY_BASE)>>16
constexpr int CAP   = 4096;            // sorted-candidate cap per image (32KB LDS)
constexpr int CAP_SPEC = 32768;        // speculative list cap per image
constexpr int GBUFB = 2048;            // passB per-block LDS buffer (u64)
constexpr float THRESH = 0.05f;
constexpr u32 KEY_BASE = 119u << 23;   // 0x3B800000
constexpr float T0     = 0.7f;
constexpr float DELTA  = 0.05f;        // conservative slack in logit space
constexpr float XQ0    = 0.797f;       // byte-quant origin; step 0.02 (floor -> conservative)
// buckets >= B_SAFE have lower bound > 0.7f, where spec is provably a superset
constexpr int B_SAFE  = ((0x3F340000u - KEY_BASE) >> 16);  // 948

// ---- workspace layout (bytes) ----
constexpr size_t WS_SCNT  = 0;                                        // N*4
constexpr size_t WS_OFLOW = 64;                                       // N*4
constexpr size_t WS_META  = 128;                                      // N*16 (.,.,done,.)
constexpr size_t WS_CTRL_WORDS = 128;                                 // 512 B zeroed
constexpr size_t WS_GHIST = 512;                                      // 16*1024*4 = 64 KB
constexpr size_t WS_BM    = WS_GHIST + (size_t)N_IMG * NB * 4;        // u8: 16*512000 = 8 MB
constexpr size_t WS_SPEC  = WS_BM + (size_t)N_IMG * (LC / 4);         // u64: 16*32768*8 = 4 MB
constexpr size_t WS_SCTR  = WS_SPEC + (size_t)N_IMG * CAP_SPEC * 8;   // N*L*4
constexpr size_t WS_XQ    = WS_SCTR + (size_t)N_IMG * L_LOC * 4;      // N*L bytes

__device__ inline float sigmoidf_acc(float x) { return 1.0f / (1.0f + expf(-x)); }

__device__ inline u32 score_bucket(u32 bits) {
    u32 b = (bits >= KEY_BASE) ? ((bits - KEY_BASE) >> 16) : 0u;
    return b > (u32)(NB - 1) ? (u32)(NB - 1) : b;
}

// ---- shared device helpers ----

// bitonic sort of sk[0..n2) descending (pads with 0 above M); barriers inside
__device__ inline void bitonic_desc(u64* sk, u32 M, int tid, int nthr) {
    u32 n2 = 1024; while (n2 < M) n2 <<= 1;
    for (u32 i = tid; i < n2; i += nthr) if (i >= M) sk[i] = 0ull;
    __syncthreads();
    for (u32 k = 2; k <= n2; k <<= 1) {
        for (u32 j = k >> 1; j > 0; j >>= 1) {
            for (u32 i = tid; i < n2; i += nthr) {
                u32 ixj = i ^ j;
                if (ixj > i) {
                    u64 a = sk[i], b = sk[ixj];
                    bool front = ((i & k) == 0);
                    if (front ? (a < b) : (a > b)) { sk[i] = b; sk[ixj] = a; }
                }
            }
            __syncthreads();
        }
    }
}

// decode + write the K output rows for image n
__device__ inline void emit_rows(int n, const u64* sk, u32 cand_slots, const u32* fill,
                                 const float* locations, const float* breg,
                                 const int* isz, float* out, int tid, int nthr) {
    float* ob = out;                                  // boxes  [N,K,4]
    float* os = out + (size_t)N_IMG * K_TOP * 4;      // scores [N,K]
    float* ol = os + (size_t)N_IMG * K_TOP;           // labels [N,K]
    float* ov = ol + (size_t)N_IMG * K_TOP;           // valid  [N,K]
    const float wimg = (float)isz[n * 2 + 1];
    const float himg = (float)isz[n * 2 + 0];
    const float* rn = breg + (size_t)n * 4 * L_LOC;
    for (int k = tid; k < K_TOP; k += nthr) {
        size_t slot = (size_t)n * K_TOP + k;
        if ((u32)k < cand_slots) {
            u64 kk = sk[k];
            u32 vb = (u32)(kk >> 32);
            u32 idx = ~(u32)(kk & 0xFFFFFFFFull);
            float val = __uint_as_float(vb);
            int loc = (int)(idx / (u32)C_CLS);
            int c = (int)(idx - (u32)loc * (u32)C_CLS);
            float lx = locations[loc * 2 + 0], ly = locations[loc * 2 + 1];
            float r0 = rn[0 * L_LOC + loc], r1 = rn[1 * L_LOC + loc];
            float r2 = rn[2 * L_LOC + loc], r3 = rn[3 * L_LOC + loc];
            float x1 = lx - r0, y1 = ly - r1, x2 = lx + r2, y2 = ly + r3;
            x1 = fminf(fmaxf(x1, 0.0f), wimg - 1.0f);
            y1 = fminf(fmaxf(y1, 0.0f), himg - 1.0f);
            x2 = fminf(fmaxf(x2, 0.0f), wimg - 1.0f);
            y2 = fminf(fmaxf(y2, 0.0f), himg - 1.0f);
            float wsz = x2 - x1 + 1.0f, hsz = y2 - y1 + 1.0f;
            bool v = (val > 0.0f) && (wsz >= 0.0f) && (hsz >= 0.0f);  // MIN_SIZE = 0
            float vf = v ? 1.0f : 0.0f;
            ob[slot * 4 + 0] = x1 * vf;
            ob[slot * 4 + 1] = y1 * vf;
            ob[slot * 4 + 2] = x2 * vf;
            ob[slot * 4 + 3] = y2 * vf;
            os[slot] = v ? sqrtf(fmaxf(val, 0.0f)) : 0.0f;
            ol[slot] = (float)(c + 1);
            ov[slot] = vf;
        } else {
            u32 fi = fill ? fill[k - (int)cand_slots] : 0u;
            ob[slot * 4 + 0] = 0.0f; ob[slot * 4 + 1] = 0.0f;
            ob[slot * 4 + 2] = 0.0f; ob[slot * 4 + 3] = 0.0f;
            os[slot] = 0.0f;
            ol[slot] = (float)((int)(fi % (u32)C_CLS) + 1);
            ov[slot] = 0.0f;
        }
    }
}

// --- kernel 1: zero control+ghist; sigmoid(centerness); byte-quantized logit threshold ---
__global__ void prep_kernel(const float* __restrict__ ctr, float* __restrict__ sctr,
                            unsigned char* __restrict__ xq, u32* __restrict__ ws32) {
    int i = blockIdx.x * blockDim.x + threadIdx.x;
    if (i < (int)WS_CTRL_WORDS) ws32[i] = 0u;
    if (i < N_IMG * NB) ws32[WS_GHIST / 4 + i] = 0u;
    if (i >= N_IMG * L_LOC) return;
    float s = sigmoidf_acc(ctr[i]);
    sctr[i] = s;
    float t = T0 / s;                       // need sigmoid(x) >= t for score >= T0
    u32 q = 255u;
    if (t < 1.0f) {
        float xm = logf(t / (1.0f - t)) - DELTA;   // logit(t) with conservative slack
        float qf = floorf((xm - XQ0) * 50.0f);      // floor -> dequant <= xm (conservative)
        q = (u32)fminf(fmaxf(qf, 0.0f), 255.0f);
    }
    xq[i] = (unsigned char)q;
}

// --- kernel 2 (hot 131-MB pass): pure streaming, ZERO side-effect-conditionals ---
// grid (5, C_CLS, N_IMG), block 256. Per thread: 5 float4 cls + 5 u32 xq loads,
// 20 fma+cmp, 5 unconditional byte stores (4-bit nibble per float4).
__global__ __launch_bounds__(256) void bitA_kernel(
        const float* __restrict__ cls, const unsigned char* __restrict__ xq,
        unsigned char* __restrict__ bm) {
    const int tid = threadIdx.x;
    const u32 n = blockIdx.z, c = blockIdx.y;
    const u32 g0 = blockIdx.x * 1280u;               // plane-local float4 offset
    const float4* cp = reinterpret_cast<const float4*>(
        cls + (size_t)n * LC + (size_t)c * L_LOC) + g0;
    const u32* xp = reinterpret_cast<const u32*>(xq + (size_t)n * L_LOC) + g0;
    unsigned char* bp = bm + (size_t)n * (LC / 4) + (size_t)c * (L_LOC / 4) + g0;
    float4 cv[5]; u32 xv[5];
#pragma unroll
    for (int q = 0; q < 5; ++q) { cv[q] = cp[q * 256 + tid]; xv[q] = xp[q * 256 + tid]; }
#pragma unroll
    for (int q = 0; q < 5; ++q) {
        u32 w = xv[q];
        float m0 = fmaf((float)(w & 255u),         0.02f, XQ0);
        float m1 = fmaf((float)((w >> 8) & 255u),  0.02f, XQ0);
        float m2 = fmaf((float)((w >> 16) & 255u), 0.02f, XQ0);
        float m3 = fmaf((float)(w >> 24),          0.02f, XQ0);
        u32 nib = (cv[q].x >= m0 ? 1u : 0u) | (cv[q].y >= m1 ? 2u : 0u)
                | (cv[q].z >= m2 ? 4u : 0u) | (cv[q].w >= m3 ? 8u : 0u);
        bp[q * 256 + tid] = (unsigned char)nib;
    }
}

// --- kernel 3: scan bitmask; survivors get exact score + hist + spec append ---
// grid (100, N_IMG), block 256. Per thread 5 u32 words (= 20 float4 = 80 elements).
__global__ __launch_bounds__(256) void passB_kernel(
        const float* __restrict__ cls, const float* __restrict__ sctr,
        const unsigned char* __restrict__ bm, u64* __restrict__ spec,
        u32* __restrict__ scnt, u32* __restrict__ oflow, u32* __restrict__ ghist) {
    __shared__ u32 lh[NB];
    __shared__ u64 sbuf[GBUFB];
    __shared__ u32 lcnt, gbase, lof;
    const int tid = threadIdx.x;
    const u32 n = blockIdx.y;
    for (int b = tid; b < NB; b += 256) lh[b] = 0u;
    if (tid == 0) { lcnt = 0; lof = 0; }
    __syncthreads();
    const u32* bw = reinterpret_cast<const u32*>(bm + (size_t)n * (LC / 4));
    const float* cls_n = cls + (size_t)n * LC;
    const float* sc_n = sctr + (size_t)n * L_LOC;
    const u32 wbase = blockIdx.x * 1280u;
    u32 wv[5];
#pragma unroll
    for (int i = 0; i < 5; ++i) wv[i] = bw[wbase + i * 256 + tid];
#pragma unroll
    for (int i = 0; i < 5; ++i) {
        u32 bits = wv[i];
        const u32 w = wbase + (u32)i * 256u + (u32)tid;   // u32 word idx = 4 float4s
        while (bits) {
            u32 b = (u32)__ffs(bits) - 1u; bits &= bits - 1u;
            u32 k = b >> 3, j = b & 7u;                   // byte k in word, element j (<4)
            u32 F = w * 4u + k;                           // global float4 index in [C][L]
            float x = cls_n[(size_t)F * 4u + j];
            u32 c = F / 6400u;                            // 6400 float4 per class plane
            u32 lf4 = F - c * 6400u;
            u32 loc = lf4 * 4u + j;
            float s = sigmoidf_acc(x);                    // exact reference formula
            float scr = s * sc_n[loc];
            u32 sb = __float_as_uint(scr);
            atomicAdd(&lh[score_bucket(sb)], 1u);
            u32 p = atomicAdd(&lcnt, 1u);
            if (p < (u32)GBUFB)
                sbuf[p] = ((u64)sb << 32) | (u32)(~(loc * (u32)C_CLS + c));
            else lof = 1u;
        }
    }
    __syncthreads();
    // sparse merge of per-block hist (few non-zero buckets)
    u32* hn = ghist + (size_t)n * NB;
    for (int b = tid; b < NB; b += 256) {
        u32 v = lh[b];
        if (v) atomicAdd(&hn[b], v);
    }
    u32 m_ = lcnt > (u32)GBUFB ? (u32)GBUFB : lcnt;
    if (tid == 0) {
        gbase = m_ ? atomicAdd(&scnt[n], m_) : 0u;
        if (lof || lcnt > (u32)GBUFB) atomicOr(&oflow[n], 1u);
        if (m_ && gbase + m_ > (u32)CAP_SPEC) atomicOr(&oflow[n], 1u);
    }
    __syncthreads();
    u64* sp = spec + (size_t)n * CAP_SPEC;
    for (u32 i = tid; i < m_; i += 256) {
        u32 pos = gbase + i;
        if (pos < (u32)CAP_SPEC) sp[pos] = sbuf[i];
    }
}

// --- kernel 4 (FAST finisher): suffix-scan ghist; filter spec (coalesced); sort; emit ---
__global__ __launch_bounds__(1024) void finishB_kernel(
        const u32* __restrict__ ghist, const u32* __restrict__ scnt,
        const u32* __restrict__ oflow, const u64* __restrict__ spec,
        u32* __restrict__ meta, const float* __restrict__ locations,
        const float* __restrict__ breg, const int* __restrict__ isz,
        float* __restrict__ out) {
    __shared__ u32 lh[NB];
    __shared__ u64 sk[CAP];
    __shared__ u32 s_b, s_cnt, s_lcnt;
    const int n = blockIdx.x;
    const int tid = threadIdx.x;
    if (oflow[n]) return;                    // slow path handles
    lh[tid] = ghist[(size_t)n * NB + tid];
    if (tid == 0) { s_b = 0xFFFFFFFFu; s_lcnt = 0; s_cnt = 0; }
    __syncthreads();
    // suffix sums: lh[b] = count with bucket >= b
    for (u32 off = 1; off < (u32)NB; off <<= 1) {
        u32 add = (tid + off < (u32)NB) ? lh[tid + off] : 0u;
        __syncthreads();
        lh[tid] += add;
        __syncthreads();
    }
    if (lh[tid] >= (u32)K_TOP && (tid == NB - 1 || lh[tid + 1] < (u32)K_TOP)) {
        s_b = (u32)tid; s_cnt = lh[tid];
    }
    __syncthreads();
    u32 bstar = s_b;
    bool valid = (bstar != 0xFFFFFFFFu) && (bstar >= (u32)B_SAFE) &&
                 (s_cnt <= (u32)CAP) && (scnt[n] <= (u32)CAP_SPEC);
    if (!valid) return;                      // meta.done stays 0 -> slowC handles
    if (tid == 0) meta[n * 4 + 2] = 1u;
    const u32 keymin = KEY_BASE + (bstar << 16);
    const u32 M = scnt[n];
    const u64* sp = spec + (size_t)n * CAP_SPEC;
    for (u32 i = tid; i < M; i += 1024) {    // coalesced u64 reads
        u64 e = sp[i];
        if ((u32)(e >> 32) >= keymin) {
            u32 p = atomicAdd(&s_lcnt, 1u);
            if (p < (u32)CAP) sk[p] = e;
        }
    }
    __syncthreads();
    u32 Mk = s_lcnt;                         // == s_cnt <= CAP, >= K
    bitonic_desc(sk, Mk, tid, 1024);
    emit_rows(n, sk, (u32)K_TOP, nullptr, locations, breg, isz, out, tid, 1024);
}

// --- kernel 5 (SLOW, gated; never taken in practice): full per-image pipeline ---
__global__ __launch_bounds__(1024) void slowC_kernel(
        const float* __restrict__ cls, const float* __restrict__ sctr,
        const u32* __restrict__ meta, const float* __restrict__ locations,
        const float* __restrict__ breg, const int* __restrict__ isz,
        float* __restrict__ out) {
    const int n = blockIdx.x;
    if (meta[n * 4 + 2] != 0u) return;
    __shared__ u32 lh[NB];                   // hist -> suffix -> scan scratch
    __shared__ u64 sk[CAP];
    __shared__ u32 fill[K_TOP];
    __shared__ u32 s_b, s_lcnt, s_filled;
    const int tid = threadIdx.x;
    lh[tid] = 0u;
    if (tid == 0) { s_b = 0xFFFFFFFFu; s_lcnt = 0; s_filled = 0; }
    __syncthreads();
    const float* cls_n = cls + (size_t)n * LC;
    const float* sc_n = sctr + (size_t)n * L_LOC;
    // phase 1: full histogram (coalesced over [C][L] plane order)
    for (u32 f = tid; f < (u32)LC; f += 1024) {
        float s = sigmoidf_acc(cls_n[f]);
        if (s > THRESH) {
            float scr = s * sc_n[f % (u32)L_LOC];
            atomicAdd(&lh[score_bucket(__float_as_uint(scr))], 1u);
        }
    }
    __syncthreads();
    // phase 2: suffix sums + cutoff
    for (u32 off = 1; off < (u32)NB; off <<= 1) {
        u32 add = (tid + off < (u32)NB) ? lh[tid + off] : 0u;
        __syncthreads();
        lh[tid] += add;
        __syncthreads();
    }
    if (lh[tid] >= (u32)K_TOP && (tid == NB - 1 || lh[tid + 1] < (u32)K_TOP))
        s_b = (u32)tid;
    __syncthreads();
    const u32 total = lh[0];
    const u32 keymin = (s_b != 0xFFFFFFFFu) ? (KEY_BASE + (s_b << 16)) : 0u;
    __syncthreads();
    // phase 3: gather candidates >= keymin
    for (u32 f = tid; f < (u32)LC; f += 1024) {
        float s = sigmoidf_acc(cls_n[f]);
        if (s > THRESH) {
            u32 loc = f % (u32)L_LOC;
            u32 c = f / (u32)L_LOC;
            float scr = s * sc_n[loc];
            u32 bits = __float_as_uint(scr);
            if (bits >= keymin) {
                u32 p = atomicAdd(&s_lcnt, 1u);
                if (p < (u32)CAP)
                    sk[p] = ((u64)bits << 32) | (u32)(~(loc * (u32)C_CLS + c));
            }
        }
    }
    __syncthreads();
    u32 M = s_lcnt > (u32)CAP ? (u32)CAP : s_lcnt;
    u32 cand_slots = total < (u32)K_TOP ? total : (u32)K_TOP;
    // phase 4: fallback fill list (smallest non-candidate flat (L,C) indices)
    if (total < (u32)K_TOP) {
        const u32 need = (u32)K_TOP - total;
        for (u32 basei = 0; basei < (u32)LC; basei += 1024) {
            u32 idx = basei + tid;
            u32 flag = 0;
            if (idx < (u32)LC) {
                u32 loc = idx / (u32)C_CLS;
                u32 c = idx - loc * (u32)C_CLS;
                float x = cls_n[(size_t)c * L_LOC + loc];
                flag = (sigmoidf_acc(x) > THRESH) ? 0u : 1u;
            }
            lh[tid] = flag;
            __syncthreads();
            for (u32 off = 1; off < 1024; off <<= 1) {
                u32 v = (tid >= (int)off) ? lh[tid - off] : 0u;
                __syncthreads();
                lh[tid] += v;
                __syncthreads();
            }
            u32 excl = lh[tid] - flag;
            u32 pos = s_filled + excl;
            if (flag && pos < need) fill[pos] = idx;
            __syncthreads();
            if (tid == 0) s_filled += lh[1023];
            __syncthreads();
            if (s_filled >= need) break;
        }
    }
    // phase 5+6: sort + emit
    bitonic_desc(sk, M, tid, 1024);
    emit_rows(n, sk, cand_slots, fill, locations, breg, isz, out, tid, 1024);
}

extern "C" void kernel_launch(void* const* d_in, const int* in_sizes, int n_in,
                              void* d_out, int out_size, void* d_ws, size_t ws_size,
                              hipStream_t stream) {
    const float* locations = (const float*)d_in[0];
    const float* cls       = (const float*)d_in[1];
    const float* breg      = (const float*)d_in[2];
    const float* ctr       = (const float*)d_in[3];
    const int*   isz       = (const int*)d_in[4];
    float* out = (float*)d_out;

    char* ws = (char*)d_ws;
    u32* ws32  = (u32*)ws;
    u32* scnt  = (u32*)(ws + WS_SCNT);
    u32* oflow = (u32*)(ws + WS_OFLOW);
    u32* meta  = (u32*)(ws + WS_META);
    u32* ghist = (u32*)(ws + WS_GHIST);
    unsigned char* bm = (unsigned char*)(ws + WS_BM);
    u64* spec  = (u64*)(ws + WS_SPEC);
    float* sctr = (float*)(ws + WS_SCTR);
    unsigned char* xq = (unsigned char*)(ws + WS_XQ);

    prep_kernel<<<(N_IMG * L_LOC + 255) / 256, 256, 0, stream>>>(ctr, sctr, xq, ws32);
    bitA_kernel<<<dim3(5, C_CLS, N_IMG), 256, 0, stream>>>(cls, xq, bm);
    passB_kernel<<<dim3(100, N_IMG), 256, 0, stream>>>(cls, sctr, bm, spec, scnt, oflow, ghist);
    finishB_kernel<<<N_IMG, 1024, 0, stream>>>(ghist, scnt, oflow, spec, meta,
                                               locations, breg, isz, out);
    slowC_kernel<<<N_IMG, 1024, 0, stream>>>(cls, sctr, meta, locations, breg, isz, out);
}

// Round 10
// 87.572 us; speedup vs baseline: 1.9017x; 1.1611x over previous
//
#include <hip/hip_runtime.h>
#include <math.h>

typedef unsigned int u32;
typedef unsigned long long u64;

constexpr int N_IMG = 16;
constexpr int C_CLS = 80;
constexpr int H_DIM = 160;
constexpr int W_DIM = 160;
constexpr int L_LOC = H_DIM * W_DIM;   // 25600
constexpr int LC    = L_LOC * C_CLS;   // 2048000
constexpr int K_TOP = 1000;
constexpr int NB    = 1024;            // histogram buckets: (bits-KEY_BASE)>>16
constexpr int CAP   = 4096;            // sorted-candidate cap per image (32KB LDS)
constexpr int CAP_SPEC = 32768;        // spec list cap per image
constexpr int GBUF  = 1024;            // megaA per-block LDS buffer (u64)
constexpr int CHUNK_L = 320;           // locations per megaA block
constexpr int CF4   = CHUNK_L / 4;     // 80 float4 per class row per block
constexpr int F4PB  = C_CLS * CF4;     // 6400 float4 per block
constexpr int F4PT  = F4PB / 256;      // 25 float4 per thread
constexpr float THRESH = 0.05f;
constexpr u32 KEY_BASE = 119u << 23;   // 0x3B800000
constexpr float T0     = 0.7f;
constexpr float DELTA  = 0.05f;        // conservative slack in logit space
// buckets >= B_SAFE have lower bound > 0.7f, where spec is provably a superset
constexpr int B_SAFE  = ((0x3F340000u - KEY_BASE) >> 16);  // 948

// ---- workspace layout (bytes) ----
constexpr size_t WS_SCNT  = 0;                                   // N*4
constexpr size_t WS_OFLOW = 64;                                  // N*4
constexpr size_t WS_META  = 128;                                 // N*16
constexpr size_t WS_CTRL_WORDS = 128;                            // 512 B zeroed
constexpr size_t WS_GHIST = 512;                                 // 16*1024*4 = 64 KB
constexpr size_t WS_SPEC  = WS_GHIST + (size_t)N_IMG * NB * 4;   // u64: 16*32768*8 = 4 MB
constexpr int ZERO_WORDS = (int)WS_CTRL_WORDS + N_IMG * NB;      // 16512 u32

__device__ inline float sigmoidf_acc(float x) { return 1.0f / (1.0f + expf(-x)); }

__device__ inline u32 score_bucket(u32 bits) {
    u32 b = (bits >= KEY_BASE) ? ((bits - KEY_BASE) >> 16) : 0u;
    return b > (u32)(NB - 1) ? (u32)(NB - 1) : b;
}

// ---- shared device helpers ----

// bitonic sort of sk[0..n2) descending (pads with 0 above M); barriers inside
__device__ inline void bitonic_desc(u64* sk, u32 M, int tid, int nthr) {
    u32 n2 = 1024; while (n2 < M) n2 <<= 1;
    for (u32 i = tid; i < n2; i += nthr) if (i >= M) sk[i] = 0ull;
    __syncthreads();
    for (u32 k = 2; k <= n2; k <<= 1) {
        for (u32 j = k >> 1; j > 0; j >>= 1) {
            for (u32 i = tid; i < n2; i += nthr) {
                u32 ixj = i ^ j;
                if (ixj > i) {
                    u64 a = sk[i], b = sk[ixj];
                    bool front = ((i & k) == 0);
                    if (front ? (a < b) : (a > b)) { sk[i] = b; sk[ixj] = a; }
                }
            }
            __syncthreads();
        }
    }
}

// decode + write the K output rows for image n
__device__ inline void emit_rows(int n, const u64* sk, u32 cand_slots, const u32* fill,
                                 const float* locations, const float* breg,
                                 const int* isz, float* out, int tid, int nthr) {
    float* ob = out;                                  // boxes  [N,K,4]
    float* os = out + (size_t)N_IMG * K_TOP * 4;      // scores [N,K]
    float* ol = os + (size_t)N_IMG * K_TOP;           // labels [N,K]
    float* ov = ol + (size_t)N_IMG * K_TOP;           // valid  [N,K]
    const float wimg = (float)isz[n * 2 + 1];
    const float himg = (float)isz[n * 2 + 0];
    const float* rn = breg + (size_t)n * 4 * L_LOC;
    for (int k = tid; k < K_TOP; k += nthr) {
        size_t slot = (size_t)n * K_TOP + k;
        if ((u32)k < cand_slots) {
            u64 kk = sk[k];
            u32 vb = (u32)(kk >> 32);
            u32 idx = ~(u32)(kk & 0xFFFFFFFFull);
            float val = __uint_as_float(vb);
            int loc = (int)(idx / (u32)C_CLS);
            int c = (int)(idx - (u32)loc * (u32)C_CLS);
            float lx = locations[loc * 2 + 0], ly = locations[loc * 2 + 1];
            float r0 = rn[0 * L_LOC + loc], r1 = rn[1 * L_LOC + loc];
            float r2 = rn[2 * L_LOC + loc], r3 = rn[3 * L_LOC + loc];
            float x1 = lx - r0, y1 = ly - r1, x2 = lx + r2, y2 = ly + r3;
            x1 = fminf(fmaxf(x1, 0.0f), wimg - 1.0f);
            y1 = fminf(fmaxf(y1, 0.0f), himg - 1.0f);
            x2 = fminf(fmaxf(x2, 0.0f), wimg - 1.0f);
            y2 = fminf(fmaxf(y2, 0.0f), himg - 1.0f);
            float wsz = x2 - x1 + 1.0f, hsz = y2 - y1 + 1.0f;
            bool v = (val > 0.0f) && (wsz >= 0.0f) && (hsz >= 0.0f);  // MIN_SIZE = 0
            float vf = v ? 1.0f : 0.0f;
            ob[slot * 4 + 0] = x1 * vf;
            ob[slot * 4 + 1] = y1 * vf;
            ob[slot * 4 + 2] = x2 * vf;
            ob[slot * 4 + 3] = y2 * vf;
            os[slot] = v ? sqrtf(fmaxf(val, 0.0f)) : 0.0f;
            ol[slot] = (float)(c + 1);
            ov[slot] = vf;
        } else {
            u32 fi = fill ? fill[k - (int)cand_slots] : 0u;
            ob[slot * 4 + 0] = 0.0f; ob[slot * 4 + 1] = 0.0f;
            ob[slot * 4 + 2] = 0.0f; ob[slot * 4 + 3] = 0.0f;
            os[slot] = 0.0f;
            ol[slot] = (float)((int)(fi % (u32)C_CLS) + 1);
            ov[slot] = 0.0f;
        }
    }
}

// --- kernel 1: zero control block + ghist ---
__global__ void prep0_kernel(u32* __restrict__ ws32) {
    int i = blockIdx.x * blockDim.x + threadIdx.x;
    if (i < ZERO_WORDS) ws32[i] = 0u;
}

// --- kernel 2 (fused hot pass): per-block 320 locations x 80 classes ---
// Prologue: sctr + logit threshold for the chunk in LDS. Stream: 25 f4/thread,
// register masks, zero side effects. Survivor phase (post-stream): ffs decode,
// L3-hot value re-read, exact score, LDS hist + append, sparse merge.
__global__ __launch_bounds__(256) void megaA_kernel(
        const float* __restrict__ cls, const float* __restrict__ ctr,
        u64* __restrict__ spec, u32* __restrict__ scnt,
        u32* __restrict__ oflow, u32* __restrict__ ghist) {
    __shared__ __align__(16) float xm[CHUNK_L];
    __shared__ float sct[CHUNK_L];
    __shared__ u32 lh[NB];
    __shared__ u64 sbuf[GBUF];
    __shared__ u32 lcnt, gbase, lof;
    const int tid = threadIdx.x;
    const u32 n = blockIdx.y;
    const u32 lbase = blockIdx.x * (u32)CHUNK_L;
    for (int b = tid; b < NB; b += 256) lh[b] = 0u;
    if (tid == 0) { lcnt = 0; lof = 0; }
    // prologue: per-location sigmoid(ctr) and logit threshold
    for (int i = tid; i < CHUNK_L; i += 256) {
        float s = sigmoidf_acc(ctr[(size_t)n * L_LOC + lbase + i]);
        sct[i] = s;
        float t = T0 / s;                   // need sigmoid(x) >= t for score >= T0
        xm[i] = (t >= 1.0f) ? 3.0e38f : (logf(t / (1.0f - t)) - DELTA);
    }
    __syncthreads();
    const float* base = cls + (size_t)n * LC + lbase;
    u32 m0 = 0u, m1 = 0u, m2 = 0u, m3 = 0u;
#pragma unroll
    for (int g = 0; g < 5; ++g) {
        float4 v[5]; u32 l4s[5];
#pragma unroll
        for (int k = 0; k < 5; ++k) {
            int q = g * 5 + k;
            u32 f = (u32)q * 256u + (u32)tid;        // f4 index in [0, 6400)
            u32 c = f / (u32)CF4;
            u32 l4 = f - c * (u32)CF4;
            l4s[k] = l4;
            v[k] = *reinterpret_cast<const float4*>(base + (size_t)c * L_LOC + l4 * 4u);
        }
#pragma unroll
        for (int k = 0; k < 5; ++k) {
            int q = g * 5 + k;
            float4 m4 = *reinterpret_cast<const float4*>(&xm[l4s[k] * 4u]);
            u32 nib = (v[k].x >= m4.x ? 1u : 0u) | (v[k].y >= m4.y ? 2u : 0u)
                    | (v[k].z >= m4.z ? 4u : 0u) | (v[k].w >= m4.w ? 8u : 0u);
            u32 sh = (u32)(q & 7) * 4u;
            if ((q >> 3) == 0) m0 |= nib << sh;
            else if ((q >> 3) == 1) m1 |= nib << sh;
            else if ((q >> 3) == 2) m2 |= nib << sh;
            else m3 |= nib << sh;
        }
    }
    // survivor phase (decoupled from the stream)
    u32 words[4] = {m0, m1, m2, m3};
#pragma unroll
    for (int w = 0; w < 4; ++w) {
        u32 bits = words[w];
        while (bits) {
            u32 b = (u32)__ffs(bits) - 1u; bits &= bits - 1u;
            u32 q = (u32)w * 8u + (b >> 2);
            u32 j = b & 3u;
            u32 f = q * 256u + (u32)tid;
            u32 c = f / (u32)CF4;
            u32 l4 = f - c * (u32)CF4;
            u32 li = l4 * 4u + j;                    // local loc index in chunk
            u32 loc = lbase + li;
            float x = base[(size_t)c * L_LOC + li];  // L3-resident re-read
            float s = sigmoidf_acc(x);               // exact reference formula
            float scr = s * sct[li];
            u32 sb = __float_as_uint(scr);
            atomicAdd(&lh[score_bucket(sb)], 1u);
            u32 p = atomicAdd(&lcnt, 1u);
            if (p < (u32)GBUF)
                sbuf[p] = ((u64)sb << 32) | (u32)(~(loc * (u32)C_CLS + c));
            else lof = 1u;
        }
    }
    __syncthreads();
    // sparse merge of per-block hist (few non-zero buckets)
    u32* hn = ghist + (size_t)n * NB;
    for (int b = tid; b < NB; b += 256) {
        u32 v = lh[b];
        if (v) atomicAdd(&hn[b], v);
    }
    u32 m_ = lcnt > (u32)GBUF ? (u32)GBUF : lcnt;
    if (tid == 0) {
        gbase = m_ ? atomicAdd(&scnt[n], m_) : 0u;
        if (lof || lcnt > (u32)GBUF) atomicOr(&oflow[n], 1u);
        if (m_ && gbase + m_ > (u32)CAP_SPEC) atomicOr(&oflow[n], 1u);
    }
    __syncthreads();
    u64* sp = spec + (size_t)n * CAP_SPEC;
    for (u32 i = tid; i < m_; i += 256) {
        u32 pos = gbase + i;
        if (pos < (u32)CAP_SPEC) sp[pos] = sbuf[i];
    }
}

// --- kernel 3: FAST finish (suffix-scan ghist; filter spec; sort; emit)
//     with inlined SLOW fallback (full rescan; never taken in practice) ---
__global__ __launch_bounds__(1024) void finishC_kernel(
        const u32* __restrict__ ghist, const u32* __restrict__ scnt,
        const u32* __restrict__ oflow, const u64* __restrict__ spec,
        const float* __restrict__ cls, const float* __restrict__ ctr,
        const float* __restrict__ locations, const float* __restrict__ breg,
        const int* __restrict__ isz, float* __restrict__ out) {
    __shared__ u32 lh[NB];
    __shared__ u64 sk[CAP];
    __shared__ u32 fill[K_TOP];
    __shared__ u32 s_b, s_cnt, s_lcnt, s_filled;
    const int n = blockIdx.x;
    const int tid = threadIdx.x;
    bool fastok = (oflow[n] == 0u);          // block-uniform
    u32 bstar = 0xFFFFFFFFu, cnt_at = 0;
    if (fastok) {
        lh[tid] = ghist[(size_t)n * NB + tid];
        if (tid == 0) { s_b = 0xFFFFFFFFu; s_lcnt = 0; s_cnt = 0; }
        __syncthreads();
        for (u32 off = 1; off < (u32)NB; off <<= 1) {   // suffix sums
            u32 add = (tid + off < (u32)NB) ? lh[tid + off] : 0u;
            __syncthreads();
            lh[tid] += add;
            __syncthreads();
        }
        if (lh[tid] >= (u32)K_TOP && (tid == NB - 1 || lh[tid + 1] < (u32)K_TOP)) {
            s_b = (u32)tid; s_cnt = lh[tid];
        }
        __syncthreads();
        bstar = s_b; cnt_at = s_cnt;
        fastok = (bstar != 0xFFFFFFFFu) && (bstar >= (u32)B_SAFE) &&
                 (cnt_at <= (u32)CAP) && (scnt[n] <= (u32)CAP_SPEC);
    }
    if (fastok) {
        const u32 keymin = KEY_BASE + (bstar << 16);
        const u32 M = scnt[n];
        const u64* sp = spec + (size_t)n * CAP_SPEC;
        for (u32 i = tid; i < M; i += 1024) {
            u64 e = sp[i];
            if ((u32)(e >> 32) >= keymin) {
                u32 p = atomicAdd(&s_lcnt, 1u);
                if (p < (u32)CAP) sk[p] = e;
            }
        }
        __syncthreads();
        u32 Mk = s_lcnt;                     // == cnt_at <= CAP, >= K
        bitonic_desc(sk, Mk, tid, 1024);
        emit_rows(n, sk, (u32)K_TOP, nullptr, locations, breg, isz, out, tid, 1024);
        return;
    }
    // ---------- SLOW path (gated; full per-image pipeline) ----------
    lh[tid] = 0u;
    if (tid == 0) { s_b = 0xFFFFFFFFu; s_lcnt = 0; s_filled = 0; }
    __syncthreads();
    const float* cls_n = cls + (size_t)n * LC;
    const float* ctr_n = ctr + (size_t)n * L_LOC;
    // phase 1: full histogram of exact scores
    for (u32 f = tid; f < (u32)LC; f += 1024) {
        float s = sigmoidf_acc(cls_n[f]);
        if (s > THRESH) {
            float scr = s * sigmoidf_acc(ctr_n[f % (u32)L_LOC]);
            atomicAdd(&lh[score_bucket(__float_as_uint(scr))], 1u);
        }
    }
    __syncthreads();
    // phase 2: suffix sums + cutoff
    for (u32 off = 1; off < (u32)NB; off <<= 1) {
        u32 add = (tid + off < (u32)NB) ? lh[tid + off] : 0u;
        __syncthreads();
        lh[tid] += add;
        __syncthreads();
    }
    if (lh[tid] >= (u32)K_TOP && (tid == NB - 1 || lh[tid + 1] < (u32)K_TOP))
        s_b = (u32)tid;
    __syncthreads();
    const u32 total = lh[0];
    const u32 keymin = (s_b != 0xFFFFFFFFu) ? (KEY_BASE + (s_b << 16)) : 0u;
    __syncthreads();
    // phase 3: gather candidates >= keymin
    for (u32 f = tid; f < (u32)LC; f += 1024) {
        float s = sigmoidf_acc(cls_n[f]);
        if (s > THRESH) {
            u32 loc = f % (u32)L_LOC;
            u32 c = f / (u32)L_LOC;
            float scr = s * sigmoidf_acc(ctr_n[loc]);
            u32 bits = __float_as_uint(scr);
            if (bits >= keymin) {
                u32 p = atomicAdd(&s_lcnt, 1u);
                if (p < (u32)CAP)
                    sk[p] = ((u64)bits << 32) | (u32)(~(loc * (u32)C_CLS + c));
            }
        }
    }
    __syncthreads();
    u32 M = s_lcnt > (u32)CAP ? (u32)CAP : s_lcnt;
    u32 cand_slots = total < (u32)K_TOP ? total : (u32)K_TOP;
    // phase 4: fallback fill list (smallest non-candidate flat (L,C) indices)
    if (total < (u32)K_TOP) {
        const u32 need = (u32)K_TOP - total;
        for (u32 basei = 0; basei < (u32)LC; basei += 1024) {
            u32 idx = basei + tid;
            u32 flag = 0;
            if (idx < (u32)LC) {
                u32 loc = idx / (u32)C_CLS;
                u32 c = idx - loc * (u32)C_CLS;
                float x = cls_n[(size_t)c * L_LOC + loc];
                flag = (sigmoidf_acc(x) > THRESH) ? 0u : 1u;
            }
            lh[tid] = flag;
            __syncthreads();
            for (u32 off = 1; off < 1024; off <<= 1) {
                u32 v = (tid >= (int)off) ? lh[tid - off] : 0u;
                __syncthreads();
                lh[tid] += v;
                __syncthreads();
            }
            u32 excl = lh[tid] - flag;
            u32 pos = s_filled + excl;
            if (flag && pos < need) fill[pos] = idx;
            __syncthreads();
            if (tid == 0) s_filled += lh[1023];
            __syncthreads();
            if (s_filled >= need) break;
        }
    }
    bitonic_desc(sk, M, tid, 1024);
    emit_rows(n, sk, cand_slots, fill, locations, breg, isz, out, tid, 1024);
}

extern "C" void kernel_launch(void* const* d_in, const int* in_sizes, int n_in,
                              void* d_out, int out_size, void* d_ws, size_t ws_size,
                              hipStream_t stream) {
    const float* locations = (const float*)d_in[0];
    const float* cls       = (const float*)d_in[1];
    const float* breg      = (const float*)d_in[2];
    const float* ctr       = (const float*)d_in[3];
    const int*   isz       = (const int*)d_in[4];
    float* out = (float*)d_out;

    char* ws = (char*)d_ws;
    u32* ws32  = (u32*)ws;
    u32* scnt  = (u32*)(ws + WS_SCNT);
    u32* oflow = (u32*)(ws + WS_OFLOW);
    u32* ghist = (u32*)(ws + WS_GHIST);
    u64* spec  = (u64*)(ws + WS_SPEC);

    prep0_kernel<<<(ZERO_WORDS + 255) / 256, 256, 0, stream>>>(ws32);
    megaA_kernel<<<dim3(L_LOC / CHUNK_L, N_IMG), 256, 0, stream>>>(
        cls, ctr, spec, scnt, oflow, ghist);
    finishC_kernel<<<N_IMG, 1024, 0, stream>>>(ghist, scnt, oflow, spec, cls, ctr,
                                               locations, breg, isz, out);
}